// Round 2
// baseline (281.252 us; speedup 1.0000x reference)
//
#include <hip/hip_runtime.h>

#define N_TOK   32768
#define NEMBED  1024
#define SCALE   32.0f   // sqrt(1024)
#define TM      16      // tokens per tile

__device__ __forceinline__ int bucket_of(int idx) {
    return (idx < 20000) ? 0 : (idx < 40000) ? 1 : (idx < 200000) ? 2 : 3;
}

// ---------------- classify + compact tokens into per-bucket lists ----------------
__global__ void classify_kernel(const int* __restrict__ x,
                                int* __restrict__ cnt,      // [4]
                                int* __restrict__ lists) {  // [4][N_TOK]
    __shared__ int s_cnt[4], s_base[4];
    int tid = threadIdx.x;
    if (tid < 4) s_cnt[tid] = 0;
    __syncthreads();
    int t = blockIdx.x * blockDim.x + tid;
    int b = 0, p = 0;
    if (t < N_TOK) {
        b = bucket_of(x[t]);
        p = atomicAdd(&s_cnt[b], 1);
    }
    __syncthreads();
    if (tid < 4) s_base[tid] = atomicAdd(&cnt[tid], s_cnt[tid]);
    __syncthreads();
    if (t < N_TOK) lists[b * N_TOK + s_base[b] + p] = t;
}

// ---------------- tile workers (called from the fused kernel) ----------------

// bucket 0: copy 16 rows of 1024 floats, scaled
__device__ __forceinline__ void do_copy_tile(const int* __restrict__ x,
                                             const float* __restrict__ table0,
                                             const int* __restrict__ list0,
                                             float* __restrict__ out,
                                             int n, int chunk,
                                             int* s_tok, int* s_row) {
    int tid = threadIdx.x;
    if (tid < TM) {
        int i = chunk * TM + tid;
        int tok = (i < n) ? list0[i] : -1;
        s_tok[tid] = tok;
        s_row[tid] = (tok >= 0) ? x[tok] : -1;
    }
    __syncthreads();
    const float4* t4 = (const float4*)table0;
    #pragma unroll 4
    for (int tt = 0; tt < TM; tt++) {
        int tok = s_tok[tt];
        if (tok >= 0) {
            float4 v = t4[(size_t)s_row[tt] * 256 + tid];
            v.x *= SCALE; v.y *= SCALE; v.z *= SCALE; v.w *= SCALE;
            ((float4*)out)[(size_t)tok * 256 + tid] = v;
        }
    }
    __syncthreads();
}

// buckets 1..3: tile = 16 tokens x 256 cols (col-slice cs of 4).
// wave w (= token group) handles tokens [4w, 4w+4); lane owns float4 of cols.
template <int D>
__device__ __forceinline__ void do_proj_tile(const int* __restrict__ x,
                                             const float* __restrict__ table,
                                             const float* __restrict__ proj,
                                             const int* __restrict__ list_b,
                                             float* __restrict__ out,
                                             int n, int start, int chunk, int cs,
                                             float* E, int* s_tok, int* s_row) {
    int tid = threadIdx.x;
    if (tid < TM) {
        int i = chunk * TM + tid;
        int tok = (i < n) ? list_b[i] : -1;
        s_tok[tid] = tok;
        s_row[tid] = (tok >= 0) ? (x[tok] - start) : -1;
    }
    __syncthreads();

    constexpr int D4 = D / 4;
    const float4* tab4 = (const float4*)table;
    float4* E4 = (float4*)E;
    for (int i4 = tid; i4 < TM * D4; i4 += 256) {
        int tt = i4 / D4, kk = i4 % D4;
        int row = s_row[tt];
        E4[i4] = (row >= 0) ? tab4[(size_t)row * D4 + kk] : make_float4(0.f, 0.f, 0.f, 0.f);
    }
    __syncthreads();

    int tg  = tid >> 6;               // 0..3 — uniform per wave
    int col = cs * 256 + (tid & 63) * 4;

    float4 acc[4];
    #pragma unroll
    for (int j = 0; j < 4; j++) acc[j] = make_float4(0.f, 0.f, 0.f, 0.f);

    for (int k0 = 0; k0 < D; k0 += 4) {
        float4 p0 = *(const float4*)(proj + (size_t)(k0 + 0) * NEMBED + col);
        float4 p1 = *(const float4*)(proj + (size_t)(k0 + 1) * NEMBED + col);
        float4 p2 = *(const float4*)(proj + (size_t)(k0 + 2) * NEMBED + col);
        float4 p3 = *(const float4*)(proj + (size_t)(k0 + 3) * NEMBED + col);
        #pragma unroll
        for (int j = 0; j < 4; j++) {
            float4 e = *(const float4*)&E[(tg * 4 + j) * D + k0];  // wave-broadcast
            acc[j].x += e.x * p0.x + e.y * p1.x + e.z * p2.x + e.w * p3.x;
            acc[j].y += e.x * p0.y + e.y * p1.y + e.z * p2.y + e.w * p3.y;
            acc[j].z += e.x * p0.z + e.y * p1.z + e.z * p2.z + e.w * p3.z;
            acc[j].w += e.x * p0.w + e.y * p1.w + e.z * p2.w + e.w * p3.w;
        }
    }

    #pragma unroll
    for (int j = 0; j < 4; j++) {
        int tok = s_tok[tg * 4 + j];
        if (tok >= 0) {
            float4 v = acc[j];
            v.x *= SCALE; v.y *= SCALE; v.z *= SCALE; v.w *= SCALE;
            *(float4*)(out + (size_t)tok * NEMBED + col) = v;
        }
    }
    __syncthreads();
}

// ---------------- fused kernel: unified tile space over all buckets ----------------
__global__ __launch_bounds__(256)
void fused_embed_kernel(const int* __restrict__ x,
                        const float* __restrict__ t0, const float* __restrict__ t1,
                        const float* __restrict__ t2, const float* __restrict__ t3,
                        const float* __restrict__ p1, const float* __restrict__ p2,
                        const float* __restrict__ p3,
                        const int* __restrict__ cnt,
                        const int* __restrict__ lists,
                        float* __restrict__ out) {
    __shared__ float E[TM * 256];
    __shared__ int s_tok[TM], s_row[TM];

    int n0 = cnt[0], n1 = cnt[1], n2 = cnt[2], n3 = cnt[3];
    int c0 = (n0 + TM - 1) / TM;
    int c1 = ((n1 + TM - 1) / TM) * 4;
    int c2 = ((n2 + TM - 1) / TM) * 4;
    int c3 = ((n3 + TM - 1) / TM) * 4;
    int total = c0 + c1 + c2 + c3;

    for (int tile = blockIdx.x; tile < total; tile += gridDim.x) {
        int r = tile;
        if (r < c0) {
            do_copy_tile(x, t0, lists, out, n0, r, s_tok, s_row);
            continue;
        }
        r -= c0;
        if (r < c1) {
            do_proj_tile<256>(x, t1, p1, lists + 1 * N_TOK, out, n1, 20000,
                              r >> 2, r & 3, E, s_tok, s_row);
            continue;
        }
        r -= c1;
        if (r < c2) {
            do_proj_tile<64>(x, t2, p2, lists + 2 * N_TOK, out, n2, 40000,
                             r >> 2, r & 3, E, s_tok, s_row);
            continue;
        }
        r -= c2;
        do_proj_tile<16>(x, t3, p3, lists + 3 * N_TOK, out, n3, 200000,
                         r >> 2, r & 3, E, s_tok, s_row);
    }
}

extern "C" void kernel_launch(void* const* d_in, const int* in_sizes, int n_in,
                              void* d_out, int out_size, void* d_ws, size_t ws_size,
                              hipStream_t stream) {
    const int*   x  = (const int*)d_in[0];
    const float* t0 = (const float*)d_in[1];
    const float* t1 = (const float*)d_in[2];
    const float* t2 = (const float*)d_in[3];
    const float* t3 = (const float*)d_in[4];
    const float* p1 = (const float*)d_in[5];
    const float* p2 = (const float*)d_in[6];
    const float* p3 = (const float*)d_in[7];
    float* out = (float*)d_out;

    int* cnt   = (int*)d_ws;          // [4] (+ padding to 64 ints)
    int* lists = cnt + 64;            // [4][N_TOK]

    hipMemsetAsync(d_ws, 0, 64 * sizeof(int), stream);
    classify_kernel<<<N_TOK / 256, 256, 0, stream>>>(x, cnt, lists);

    fused_embed_kernel<<<4096, 256, 0, stream>>>(x, t0, t1, t2, t3, p1, p2, p3,
                                                 cnt, lists, out);
}

// Round 3
// 244.368 us; speedup vs baseline: 1.1509x; 1.1509x over previous
//
#include <hip/hip_runtime.h>

#define N_TOK   32768
#define NEMBED  1024
#define SCALE   32.0f   // sqrt(1024)
#define TM      16      // tokens per tile

// static grid partition (by approx FLOP share per bucket)
#define G0 128
#define G1 1152
#define G2 2304
#define G3 512
#define GRID (G0 + G1 + G2 + G3)   // 4096

__device__ __forceinline__ int bucket_of(int idx) {
    return (idx < 20000) ? 0 : (idx < 40000) ? 1 : (idx < 200000) ? 2 : 3;
}

// ---------------- classify + compact tokens into per-bucket lists ----------------
__global__ void classify_kernel(const int* __restrict__ x,
                                int* __restrict__ cnt,      // [4]
                                int* __restrict__ lists) {  // [4][N_TOK]
    __shared__ int s_cnt[4], s_base[4];
    int tid = threadIdx.x;
    if (tid < 4) s_cnt[tid] = 0;
    __syncthreads();
    int t = blockIdx.x * blockDim.x + tid;
    int b = 0, p = 0;
    if (t < N_TOK) {
        b = bucket_of(x[t]);
        p = atomicAdd(&s_cnt[b], 1);
    }
    __syncthreads();
    if (tid < 4) s_base[tid] = atomicAdd(&cnt[tid], s_cnt[tid]);
    __syncthreads();
    if (t < N_TOK) lists[b * N_TOK + s_base[b] + p] = t;
}

// ---------------- tile workers ----------------

// bucket 0: copy 16 rows of 1024 floats, scaled
__device__ __forceinline__ void do_copy_tile(const int* __restrict__ x,
                                             const float* __restrict__ table0,
                                             const int* __restrict__ list0,
                                             float* __restrict__ out,
                                             int n, int chunk,
                                             int* s_tok, int* s_row) {
    int tid = threadIdx.x;
    if (tid < TM) {
        int i = chunk * TM + tid;
        int tok = (i < n) ? list0[i] : -1;
        s_tok[tid] = tok;
        s_row[tid] = (tok >= 0) ? x[tok] : -1;
    }
    __syncthreads();
    const float4* t4 = (const float4*)table0;
    #pragma unroll 4
    for (int tt = 0; tt < TM; tt++) {
        int tok = s_tok[tt];
        if (tok >= 0) {
            float4 v = t4[(size_t)s_row[tt] * 256 + tid];
            v.x *= SCALE; v.y *= SCALE; v.z *= SCALE; v.w *= SCALE;
            ((float4*)out)[(size_t)tok * 256 + tid] = v;
        }
    }
    __syncthreads();
}

// buckets 1..3: tile = 16 tokens x 256 cols (col-slice cs of 4).
// wave w (= token group) handles tokens [4w, 4w+4); lane owns float4 of cols.
template <int D>
__device__ __forceinline__ void do_proj_tile(const int* __restrict__ x,
                                             const float* __restrict__ table,
                                             const float* __restrict__ proj,
                                             const int* __restrict__ list_b,
                                             float* __restrict__ out,
                                             int n, int start, int chunk, int cs,
                                             float* E, int* s_tok, int* s_row) {
    int tid = threadIdx.x;
    if (tid < TM) {
        int i = chunk * TM + tid;
        int tok = (i < n) ? list_b[i] : -1;
        s_tok[tid] = tok;
        s_row[tid] = (tok >= 0) ? (x[tok] - start) : -1;
    }
    __syncthreads();

    constexpr int D4 = D / 4;
    const float4* tab4 = (const float4*)table;
    float4* E4 = (float4*)E;
    for (int i4 = tid; i4 < TM * D4; i4 += 256) {
        int tt = i4 / D4, kk = i4 % D4;
        int row = s_row[tt];
        E4[i4] = (row >= 0) ? tab4[(size_t)row * D4 + kk] : make_float4(0.f, 0.f, 0.f, 0.f);
    }
    __syncthreads();

    int tg  = threadIdx.x >> 6;             // 0..3 — uniform per wave
    int col = cs * 256 + (threadIdx.x & 63) * 4;

    float4 acc[4];
    #pragma unroll
    for (int j = 0; j < 4; j++) acc[j] = make_float4(0.f, 0.f, 0.f, 0.f);

    for (int k0 = 0; k0 < D; k0 += 4) {
        float4 p0 = *(const float4*)(proj + (size_t)(k0 + 0) * NEMBED + col);
        float4 p1 = *(const float4*)(proj + (size_t)(k0 + 1) * NEMBED + col);
        float4 p2 = *(const float4*)(proj + (size_t)(k0 + 2) * NEMBED + col);
        float4 p3 = *(const float4*)(proj + (size_t)(k0 + 3) * NEMBED + col);
        #pragma unroll
        for (int j = 0; j < 4; j++) {
            float4 e = *(const float4*)&E[(tg * 4 + j) * D + k0];  // wave-broadcast
            acc[j].x += e.x * p0.x + e.y * p1.x + e.z * p2.x + e.w * p3.x;
            acc[j].y += e.x * p0.y + e.y * p1.y + e.z * p2.y + e.w * p3.y;
            acc[j].z += e.x * p0.z + e.y * p1.z + e.z * p2.z + e.w * p3.z;
            acc[j].w += e.x * p0.w + e.y * p1.w + e.z * p2.w + e.w * p3.w;
        }
    }

    #pragma unroll
    for (int j = 0; j < 4; j++) {
        int tok = s_tok[tg * 4 + j];
        if (tok >= 0) {
            float4 v = acc[j];
            v.x *= SCALE; v.y *= SCALE; v.z *= SCALE; v.w *= SCALE;
            *(float4*)(out + (size_t)tok * NEMBED + col) = v;
        }
    }
    __syncthreads();
}

// ---------------- fused kernel: static block partition, uniform per-block type ----------------
__global__ __launch_bounds__(256)
void fused_embed_kernel(const int* __restrict__ x,
                        const float* __restrict__ t0, const float* __restrict__ t1,
                        const float* __restrict__ t2, const float* __restrict__ t3,
                        const float* __restrict__ p1, const float* __restrict__ p2,
                        const float* __restrict__ p3,
                        const int* __restrict__ cnt,
                        const int* __restrict__ lists,
                        float* __restrict__ out) {
    __shared__ float E[TM * 256];
    __shared__ int s_tok[TM], s_row[TM];

    int bid = blockIdx.x;
    if (bid < G0) {
        int n = cnt[0];
        int ntiles = (n + TM - 1) / TM;
        for (int t = bid; t < ntiles; t += G0)
            do_copy_tile(x, t0, lists, out, n, t, s_tok, s_row);
    } else if (bid < G0 + G1) {
        int n = cnt[1];
        int ntiles = ((n + TM - 1) / TM) * 4;
        for (int t = bid - G0; t < ntiles; t += G1)
            do_proj_tile<256>(x, t1, p1, lists + 1 * N_TOK, out, n, 20000,
                              t >> 2, t & 3, E, s_tok, s_row);
    } else if (bid < G0 + G1 + G2) {
        int n = cnt[2];
        int ntiles = ((n + TM - 1) / TM) * 4;
        for (int t = bid - (G0 + G1); t < ntiles; t += G2)
            do_proj_tile<64>(x, t2, p2, lists + 2 * N_TOK, out, n, 40000,
                             t >> 2, t & 3, E, s_tok, s_row);
    } else {
        int n = cnt[3];
        int ntiles = ((n + TM - 1) / TM) * 4;
        for (int t = bid - (G0 + G1 + G2); t < ntiles; t += G3)
            do_proj_tile<16>(x, t3, p3, lists + 3 * N_TOK, out, n, 200000,
                             t >> 2, t & 3, E, s_tok, s_row);
    }
}

extern "C" void kernel_launch(void* const* d_in, const int* in_sizes, int n_in,
                              void* d_out, int out_size, void* d_ws, size_t ws_size,
                              hipStream_t stream) {
    const int*   x  = (const int*)d_in[0];
    const float* t0 = (const float*)d_in[1];
    const float* t1 = (const float*)d_in[2];
    const float* t2 = (const float*)d_in[3];
    const float* t3 = (const float*)d_in[4];
    const float* p1 = (const float*)d_in[5];
    const float* p2 = (const float*)d_in[6];
    const float* p3 = (const float*)d_in[7];
    float* out = (float*)d_out;

    int* cnt   = (int*)d_ws;          // [4] (+ padding to 64 ints)
    int* lists = cnt + 64;            // [4][N_TOK]

    hipMemsetAsync(d_ws, 0, 64 * sizeof(int), stream);
    classify_kernel<<<N_TOK / 256, 256, 0, stream>>>(x, cnt, lists);

    fused_embed_kernel<<<GRID, 256, 0, stream>>>(x, t0, t1, t2, t3, p1, p2, p3,
                                                 cnt, lists, out);
}

// Round 4
// 118.713 us; speedup vs baseline: 2.3692x; 2.0585x over previous
//
#include <hip/hip_runtime.h>

#define N_TOK   32768
#define NEMBED  1024
#define SCALE   32.0f   // sqrt(1024)
#define TM      16      // tokens per tile

// static grid partition, weighted by max(FLOPs, bytes) per bucket
#define G0 128
#define G1 1088
#define G2 2304
#define G3 576
#define GRID (G0 + G1 + G2 + G3)   // 4096

__device__ __forceinline__ int bucket_of(int idx) {
    return (idx < 20000) ? 0 : (idx < 40000) ? 1 : (idx < 200000) ? 2 : 3;
}

// ---------------- classify + compact tokens into per-bucket lists ----------------
__global__ void classify_kernel(const int* __restrict__ x,
                                int* __restrict__ cnt,      // [4]
                                int* __restrict__ lists) {  // [4][N_TOK]
    __shared__ int s_cnt[4], s_base[4];
    int tid = threadIdx.x;
    if (tid < 4) s_cnt[tid] = 0;
    __syncthreads();
    int t = blockIdx.x * blockDim.x + tid;
    int b = 0, p = 0;
    if (t < N_TOK) {
        b = bucket_of(x[t]);
        p = atomicAdd(&s_cnt[b], 1);
    }
    __syncthreads();
    if (tid < 4) s_base[tid] = atomicAdd(&cnt[tid], s_cnt[tid]);
    __syncthreads();
    if (t < N_TOK) lists[b * N_TOK + s_base[b] + p] = t;
}

// ---------------- tile workers ----------------

// bucket 0: copy 16 rows of 1024 floats, scaled
__device__ __forceinline__ void do_copy_tile(const int* __restrict__ x,
                                             const float* __restrict__ table0,
                                             const int* __restrict__ list0,
                                             float* __restrict__ out,
                                             int n, int chunk,
                                             int* s_tok, int* s_row) {
    int tid = threadIdx.x;
    if (tid < TM) {
        int i = chunk * TM + tid;
        int tok = (i < n) ? list0[i] : -1;
        s_tok[tid] = tok;
        s_row[tid] = (tok >= 0) ? x[tok] : -1;
    }
    __syncthreads();
    const float4* t4 = (const float4*)table0;
    #pragma unroll 1
    for (int tt = 0; tt < TM; tt++) {
        int tok = s_tok[tt];
        if (tok >= 0) {
            float4 v = t4[(size_t)s_row[tt] * 256 + tid];
            v.x *= SCALE; v.y *= SCALE; v.z *= SCALE; v.w *= SCALE;
            ((float4*)out)[(size_t)tok * 256 + tid] = v;
        }
    }
    __syncthreads();
}

// buckets 1..3: tile = 16 tokens x 256 cols (col-slice cs of 4).
// wave w (= token group) handles tokens [4w, 4w+4); lane owns float4 of cols.
template <int D>
__device__ __forceinline__ void do_proj_tile(const int* __restrict__ x,
                                             const float* __restrict__ table,
                                             const float* __restrict__ proj,
                                             const int* __restrict__ list_b,
                                             float* __restrict__ out,
                                             int n, int start, int chunk, int cs,
                                             float* E, int* s_tok, int* s_row) {
    int tid = threadIdx.x;
    if (tid < TM) {
        int i = chunk * TM + tid;
        int tok = (i < n) ? list_b[i] : -1;
        s_tok[tid] = tok;
        s_row[tid] = (tok >= 0) ? (x[tok] - start) : -1;
    }
    __syncthreads();

    constexpr int D4 = D / 4;
    const float4* tab4 = (const float4*)table;
    float4* E4 = (float4*)E;
    #pragma unroll 1
    for (int i4 = tid; i4 < TM * D4; i4 += 256) {
        int tt = i4 / D4, kk = i4 % D4;
        int row = s_row[tt];
        E4[i4] = (row >= 0) ? tab4[(size_t)row * D4 + kk] : make_float4(0.f, 0.f, 0.f, 0.f);
    }
    __syncthreads();

    int tg  = threadIdx.x >> 6;             // 0..3 — uniform per wave
    int col = cs * 256 + (threadIdx.x & 63) * 4;

    float4 acc[4];
    #pragma unroll
    for (int j = 0; j < 4; j++) acc[j] = make_float4(0.f, 0.f, 0.f, 0.f);

    // cap unroll: 4 k-steps in flight = 16 live p float4s max — keeps VGPR ~100
    #pragma unroll 4
    for (int k0 = 0; k0 < D; k0 += 4) {
        float4 p0 = *(const float4*)(proj + (size_t)(k0 + 0) * NEMBED + col);
        float4 p1 = *(const float4*)(proj + (size_t)(k0 + 1) * NEMBED + col);
        float4 p2 = *(const float4*)(proj + (size_t)(k0 + 2) * NEMBED + col);
        float4 p3 = *(const float4*)(proj + (size_t)(k0 + 3) * NEMBED + col);
        #pragma unroll
        for (int j = 0; j < 4; j++) {
            float4 e = *(const float4*)&E[(tg * 4 + j) * D + k0];  // wave-broadcast
            acc[j].x += e.x * p0.x + e.y * p1.x + e.z * p2.x + e.w * p3.x;
            acc[j].y += e.x * p0.y + e.y * p1.y + e.z * p2.y + e.w * p3.y;
            acc[j].z += e.x * p0.z + e.y * p1.z + e.z * p2.z + e.w * p3.z;
            acc[j].w += e.x * p0.w + e.y * p1.w + e.z * p2.w + e.w * p3.w;
        }
    }

    #pragma unroll
    for (int j = 0; j < 4; j++) {
        int tok = s_tok[tg * 4 + j];
        if (tok >= 0) {
            float4 v = acc[j];
            v.x *= SCALE; v.y *= SCALE; v.z *= SCALE; v.w *= SCALE;
            *(float4*)(out + (size_t)tok * NEMBED + col) = v;
        }
    }
    __syncthreads();
}

// ---------------- fused kernel: static block partition, uniform per-block type ----------------
__global__ __launch_bounds__(256, 4)   // force VGPR <= 128
void fused_embed_kernel(const int* __restrict__ x,
                        const float* __restrict__ t0, const float* __restrict__ t1,
                        const float* __restrict__ t2, const float* __restrict__ t3,
                        const float* __restrict__ p1, const float* __restrict__ p2,
                        const float* __restrict__ p3,
                        const int* __restrict__ cnt,
                        const int* __restrict__ lists,
                        float* __restrict__ out) {
    __shared__ float E[TM * 256];
    __shared__ int s_tok[TM], s_row[TM];

    int bid = blockIdx.x;
    if (bid < G0) {
        int n = cnt[0];
        int ntiles = (n + TM - 1) / TM;
        #pragma unroll 1
        for (int t = bid; t < ntiles; t += G0)
            do_copy_tile(x, t0, lists, out, n, t, s_tok, s_row);
    } else if (bid < G0 + G1) {
        int n = cnt[1];
        int ntiles = ((n + TM - 1) / TM) * 4;
        #pragma unroll 1
        for (int t = bid - G0; t < ntiles; t += G1)
            do_proj_tile<256>(x, t1, p1, lists + 1 * N_TOK, out, n, 20000,
                              t >> 2, t & 3, E, s_tok, s_row);
    } else if (bid < G0 + G1 + G2) {
        int n = cnt[2];
        int ntiles = ((n + TM - 1) / TM) * 4;
        #pragma unroll 1
        for (int t = bid - (G0 + G1); t < ntiles; t += G2)
            do_proj_tile<64>(x, t2, p2, lists + 2 * N_TOK, out, n, 40000,
                             t >> 2, t & 3, E, s_tok, s_row);
    } else {
        int n = cnt[3];
        int ntiles = ((n + TM - 1) / TM) * 4;
        #pragma unroll 1
        for (int t = bid - (G0 + G1 + G2); t < ntiles; t += G3)
            do_proj_tile<16>(x, t3, p3, lists + 3 * N_TOK, out, n, 200000,
                             t >> 2, t & 3, E, s_tok, s_row);
    }
}

extern "C" void kernel_launch(void* const* d_in, const int* in_sizes, int n_in,
                              void* d_out, int out_size, void* d_ws, size_t ws_size,
                              hipStream_t stream) {
    const int*   x  = (const int*)d_in[0];
    const float* t0 = (const float*)d_in[1];
    const float* t1 = (const float*)d_in[2];
    const float* t2 = (const float*)d_in[3];
    const float* t3 = (const float*)d_in[4];
    const float* p1 = (const float*)d_in[5];
    const float* p2 = (const float*)d_in[6];
    const float* p3 = (const float*)d_in[7];
    float* out = (float*)d_out;

    int* cnt   = (int*)d_ws;          // [4] (+ padding to 64 ints)
    int* lists = cnt + 64;            // [4][N_TOK]

    hipMemsetAsync(d_ws, 0, 64 * sizeof(int), stream);
    classify_kernel<<<N_TOK / 256, 256, 0, stream>>>(x, cnt, lists);

    fused_embed_kernel<<<GRID, 256, 0, stream>>>(x, t0, t1, t2, t3, p1, p2, p3,
                                                 cnt, lists, out);
}